// Round 1
// baseline (44.555 us; speedup 1.0000x reference)
//
#include <hip/hip_runtime.h>
#include <math.h>

#define NQ 8
#define NL 3
#define NC 3
#define BATCH 16384

// Layout: 16 lanes per batch element, each lane holds 16 complex amplitudes.
// Amplitude index a[7:0]: bits 0..3 = register index r (wires 0..3),
//                         bits 4..7 = lane sub-id q (wires 4..7).
// Wire i <-> bit i of the amplitude index (self-consistent; measurement is
// defined per-wire so reference flat order doesn't matter).

__global__ __launch_bounds__(256) void vqc_kernel(
    const float* __restrict__ x, const float* __restrict__ qw,
    const float* __restrict__ W, const float* __restrict__ b,
    float* __restrict__ out)
{
  const int tid  = threadIdx.x;
  const int lane = tid & 63;
  const int q    = lane & 15;                    // sub-id within 16-lane group
  const int elem = blockIdx.x * 16 + (tid >> 4); // one element per 16 lanes

  // lane q<8 holds x[elem*8+q]; broadcast later via __shfl(.,w,16)
  float xv = 0.f;
  if (q < NQ) xv = x[elem * NQ + q];

  float sr[16], si[16];
  #pragma unroll
  for (int r = 0; r < 16; ++r) { sr[r] = 0.f; si[r] = 0.f; }
  if (q == 0) sr[0] = 1.f;  // |0...0>

  const float PI = 3.14159265358979323846f;

  #pragma unroll
  for (int layer = 0; layer < NL; ++layer) {
    const int base = layer * 2 * NQ;

    // ---------------- RY gates (theta = pi*x_i + w_i) ----------------
    #pragma unroll
    for (int w = 0; w < NQ; ++w) {
      const float ang = 0.5f * (PI * __shfl(xv, w, 16) + qw[base + w]);
      const float s = __sinf(ang);
      const float c = __cosf(ang);
      if (w < 4) {
        // register-bit wire: in-register 2x2 rotation on pairs
        const int m = 1 << w;
        #pragma unroll
        for (int r = 0; r < 16; ++r) {
          if (!(r & m)) {
            const int r1 = r | m;
            const float a0r = sr[r],  a0i = si[r];
            const float a1r = sr[r1], a1i = si[r1];
            sr[r]  = c * a0r - s * a1r;
            si[r]  = c * a0i - s * a1i;
            sr[r1] = s * a0r + c * a1r;
            si[r1] = s * a0i + c * a1i;
          }
        }
      } else {
        // lane-bit wire: exchange with partner lane, fused sign
        const int lm = 1 << (w - 4);
        const float ss = (q & lm) ? s : -s;
        #pragma unroll
        for (int r = 0; r < 16; ++r) {
          const float otr = __shfl_xor(sr[r], lm);
          const float oti = __shfl_xor(si[r], lm);
          sr[r] = c * sr[r] + ss * otr;
          si[r] = c * si[r] + ss * oti;
        }
      }
    }

    // ---------------- CNOT chain: (0,1)..(6,7),(7,0) ----------------
    // (0,1),(1,2),(2,3): both bits in-register -> pure register permutation
    #pragma unroll
    for (int cw = 0; cw < 3; ++cw) {
      const int cm = 1 << cw, tm = 1 << (cw + 1);
      #pragma unroll
      for (int r = 0; r < 16; ++r) {
        if ((r & cm) && !(r & tm)) {
          const int r1 = r | tm;
          const float tr = sr[r], ti = si[r];
          sr[r]  = sr[r1]; si[r]  = si[r1];
          sr[r1] = tr;     si[r1] = ti;
        }
      }
    }
    // (3,4): ctrl = reg bit 3, tgt = lane bit 0 -> shuffle-swap on r with bit3
    #pragma unroll
    for (int r = 0; r < 16; ++r) {
      if (r & 8) {
        sr[r] = __shfl_xor(sr[r], 1);
        si[r] = __shfl_xor(si[r], 1);
      }
    }
    // (4,5),(5,6),(6,7): both lane bits -> shuffle + predicated take
    #pragma unroll
    for (int cw = 4; cw < 7; ++cw) {
      const int clm = 1 << (cw - 4);
      const int tlm = 1 << (cw - 3);
      const bool cb = (q & clm) != 0;
      #pragma unroll
      for (int r = 0; r < 16; ++r) {
        const float vr = __shfl_xor(sr[r], tlm);
        const float vi = __shfl_xor(si[r], tlm);
        if (cb) { sr[r] = vr; si[r] = vi; }
      }
    }
    // (7,0): ctrl = lane bit 3, tgt = reg bit 0 -> predicated local swap
    {
      const bool cb = (q & 8) != 0;
      if (cb) {
        #pragma unroll
        for (int r = 0; r < 16; r += 2) {
          const float tr = sr[r], ti = si[r];
          sr[r]   = sr[r+1]; si[r]   = si[r+1];
          sr[r+1] = tr;      si[r+1] = ti;
        }
      }
    }

    // ---------------- RZ gates (theta = w_{base+8+i}) ----------------
    #pragma unroll
    for (int w = 0; w < NQ; ++w) {
      const float ang = 0.5f * qw[base + NQ + w];
      const float s = __sinf(ang);
      const float c = __cosf(ang);
      if (w < 4) {
        const int m = 1 << w;
        #pragma unroll
        for (int r = 0; r < 16; ++r) {
          const float sg = (r & m) ? s : -s;
          const float re = sr[r], im = si[r];
          sr[r] = c * re - sg * im;
          si[r] = c * im + sg * re;
        }
      } else {
        const int lm = 1 << (w - 4);
        const float sg = (q & lm) ? s : -s;
        #pragma unroll
        for (int r = 0; r < 16; ++r) {
          const float re = sr[r], im = si[r];
          sr[r] = c * re - sg * im;
          si[r] = c * im + sg * re;
        }
      }
    }
  }

  // ---------------- measurement: <Z_j> for wires 0,1,2 (register bits) ----
  float z0 = 0.f, z1 = 0.f, z2 = 0.f;
  #pragma unroll
  for (int r = 0; r < 16; ++r) {
    const float p = sr[r]*sr[r] + si[r]*si[r];
    z0 += (r & 1) ? -p : p;
    z1 += (r & 2) ? -p : p;
    z2 += (r & 4) ? -p : p;
  }
  // butterfly reduce across the 16-lane group
  #pragma unroll
  for (int m = 1; m <= 8; m <<= 1) {
    z0 += __shfl_xor(z0, m);
    z1 += __shfl_xor(z1, m);
    z2 += __shfl_xor(z2, m);
  }

  // linear head: out[e,c] = b[c] + sum_j W[c,j] * z_j ; lanes q=0..2 write
  if (q < NC) {
    const float acc = b[q] + W[q*3+0]*z0 + W[q*3+1]*z1 + W[q*3+2]*z2;
    out[elem * NC + q] = acc;
  }
}

extern "C" void kernel_launch(void* const* d_in, const int* in_sizes, int n_in,
                              void* d_out, int out_size, void* d_ws, size_t ws_size,
                              hipStream_t stream) {
  const float* x  = (const float*)d_in[0];
  const float* qw = (const float*)d_in[1];
  const float* W  = (const float*)d_in[2];
  const float* b  = (const float*)d_in[3];
  float* out = (float*)d_out;

  dim3 grid(BATCH / 16);   // 16 elements per 256-thread block
  vqc_kernel<<<grid, 256, 0, stream>>>(x, qw, W, b, out);
}

// Round 2
// 31.714 us; speedup vs baseline: 1.4049x; 1.4049x over previous
//
#include <hip/hip_runtime.h>
#include <math.h>

#define NQ 8
#define NL 3
#define NC 3
#define BATCH 16384

// Layout: 16 lanes per batch element, each lane holds 16 complex amplitudes.
// Amplitude index a[7:0]: bits 0..3 = register index r (wires 0..3),
//                         bits 4..7 = lane sub-id q (wires 4..7).
//
// Algebraic fusions vs round-1 kernel:
//  - CNOT chain (0,1)(1,2)...(6,7)(7,0) composed into one linear index map L:
//      B0 = b0^P (P = parity of all), Bk = b0^...^bk.
//    Implemented as a single pull: dest (r,q) <- src (rc, qs) with
//      rc = ((r ^ (r<<1)) & 15) ^ (laneBit3 ? 3 : 0)
//      qs = ((q ^ (q<<1)) & 15) ^ (regBit3  ? 1 : 0)
//  - RZ layer fused into one per-amplitude phase e^{i phi(a)},
//    phi built by a butterfly over the 4 reg-wire half-angles + lane part.
//  - Final layer: CNOT chain + RZ dropped entirely; chain folded into
//    measurement signs: bit0(L)=parity(b1..b7), bit1(L)=b0^b1, bit2(L)=b0^b1^b2.

__global__ __launch_bounds__(256, 4) void vqc_kernel(
    const float* __restrict__ x, const float* __restrict__ qw,
    const float* __restrict__ W, const float* __restrict__ b,
    float* __restrict__ out)
{
  const int tid  = threadIdx.x;
  const int q    = tid & 15;                     // sub-id within 16-lane group
  const int elem = blockIdx.x * 16 + (tid >> 4); // one element per 16 lanes

  float xv = 0.f;
  if (q < NQ) xv = x[elem * NQ + q];

  float sr[16], si[16];
  #pragma unroll
  for (int r = 0; r < 16; ++r) { sr[r] = 0.f; si[r] = 0.f; }
  if (q == 0) sr[0] = 1.f;  // |0...0>

  const float PI = 3.14159265358979323846f;

  // per-thread source-lane indices for the composed CNOT pull
  const int  qs0 = (q ^ (q << 1)) & 15;
  const int  qs1 = qs0 ^ 1;
  const bool laneB7 = (q & 8) != 0;

  #pragma unroll
  for (int layer = 0; layer < NL; ++layer) {
    const int base = layer * 2 * NQ;

    // ---------------- RY (theta = pi*x_w + qw[base+w]) ----------------
    // lane q (<8) computes its own angle + sincos once; broadcast per wire.
    float cv, sv;
    {
      const float ang = 0.5f * (PI * xv + qw[base + q]); // q>=8: harmless
      __sincosf(ang, &sv, &cv);
    }
    #pragma unroll
    for (int w = 0; w < NQ; ++w) {
      const float c = __shfl(cv, w, 16);
      const float s = __shfl(sv, w, 16);
      if (w < 4) {
        const int m = 1 << w;
        #pragma unroll
        for (int r = 0; r < 16; ++r) {
          if (!(r & m)) {
            const int r1 = r | m;
            const float a0r = sr[r],  a0i = si[r];
            const float a1r = sr[r1], a1i = si[r1];
            sr[r]  = c * a0r - s * a1r;
            si[r]  = c * a0i - s * a1i;
            sr[r1] = s * a0r + c * a1r;
            si[r1] = s * a0i + c * a1i;
          }
        }
      } else {
        const int lm = 1 << (w - 4);
        const float ss = (q & lm) ? s : -s;
        #pragma unroll
        for (int r = 0; r < 16; ++r) {
          const float otr = __shfl_xor(sr[r], lm);
          const float oti = __shfl_xor(si[r], lm);
          sr[r] = c * sr[r] + ss * otr;
          si[r] = c * si[r] + ss * oti;
        }
      }
    }

    if (layer < NL - 1) {
      // ------------- composed CNOT chain (single permutation pull) -------
      {
        float nr[16], ni[16];
        #pragma unroll
        for (int r = 0; r < 16; ++r) {
          const int rc0  = (r ^ (r << 1)) & 15;   // compile-time
          const int rc1  = rc0 ^ 3;               // compile-time
          const int qsel = (r & 8) ? qs1 : qs0;   // compile-time var select
          const float u0r = __shfl(sr[rc0], qsel, 16);
          const float u0i = __shfl(si[rc0], qsel, 16);
          const float u1r = __shfl(sr[rc1], qsel, 16);
          const float u1i = __shfl(si[rc1], qsel, 16);
          nr[r] = laneB7 ? u1r : u0r;
          ni[r] = laneB7 ? u1i : u0i;
        }
        #pragma unroll
        for (int r = 0; r < 16; ++r) { sr[r] = nr[r]; si[r] = ni[r]; }
      }

      // ------------- fused RZ: one phase per amplitude -------------------
      {
        const float h0 = 0.5f * qw[base + NQ + 0];
        const float h1 = 0.5f * qw[base + NQ + 1];
        const float h2 = 0.5f * qw[base + NQ + 2];
        const float h3 = 0.5f * qw[base + NQ + 3];
        const float h4 = 0.5f * qw[base + NQ + 4];
        const float h5 = 0.5f * qw[base + NQ + 5];
        const float h6 = 0.5f * qw[base + NQ + 6];
        const float h7 = 0.5f * qw[base + NQ + 7];
        const float Lq = ((q & 1) ? h4 : -h4) + ((q & 2) ? h5 : -h5)
                       + ((q & 4) ? h6 : -h6) + ((q & 8) ? h7 : -h7);
        float R[16];
        R[0] = Lq - h0; R[1] = Lq + h0;
        #pragma unroll
        for (int r = 0; r < 2; ++r) { R[r + 2] = R[r] + h1; R[r] -= h1; }
        #pragma unroll
        for (int r = 0; r < 4; ++r) { R[r + 4] = R[r] + h2; R[r] -= h2; }
        #pragma unroll
        for (int r = 0; r < 8; ++r) { R[r + 8] = R[r] + h3; R[r] -= h3; }
        #pragma unroll
        for (int r = 0; r < 16; ++r) {
          float sp, cp;
          __sincosf(R[r], &sp, &cp);
          const float re = sr[r], im = si[r];
          sr[r] = cp * re - sp * im;
          si[r] = cp * im + sp * re;
        }
      }
    }
  }

  // -------- measurement with final CNOT chain folded into signs ----------
  // bit0(L(a)) = parity(b1..b7) = parity(r&14) ^ parity(q)
  // bit1(L(a)) = b0^b1          = parity(r&3)
  // bit2(L(a)) = b0^b1^b2       = parity(r&7)
  float z0 = 0.f, z1 = 0.f, z2 = 0.f;
  #pragma unroll
  for (int r = 0; r < 16; ++r) {
    const float p = sr[r] * sr[r] + si[r] * si[r];
    z0 += (__popc(r & 14) & 1) ? -p : p;  // compile-time signs
    z1 += (__popc(r & 3)  & 1) ? -p : p;
    z2 += (__popc(r & 7)  & 1) ? -p : p;
  }
  if (__popc(q) & 1) z0 = -z0;

  #pragma unroll
  for (int m = 1; m <= 8; m <<= 1) {
    z0 += __shfl_xor(z0, m);
    z1 += __shfl_xor(z1, m);
    z2 += __shfl_xor(z2, m);
  }

  if (q < NC) {
    out[elem * NC + q] = b[q] + W[q * 3 + 0] * z0 + W[q * 3 + 1] * z1
                              + W[q * 3 + 2] * z2;
  }
}

extern "C" void kernel_launch(void* const* d_in, const int* in_sizes, int n_in,
                              void* d_out, int out_size, void* d_ws, size_t ws_size,
                              hipStream_t stream) {
  const float* x  = (const float*)d_in[0];
  const float* qw = (const float*)d_in[1];
  const float* W  = (const float*)d_in[2];
  const float* b  = (const float*)d_in[3];
  float* out = (float*)d_out;

  dim3 grid(BATCH / 16);   // 16 elements per 256-thread block
  vqc_kernel<<<grid, 256, 0, stream>>>(x, qw, W, b, out);
}

// Round 3
// 28.548 us; speedup vs baseline: 1.5607x; 1.1109x over previous
//
#include <hip/hip_runtime.h>
#include <math.h>

#define NQ 8
#define NL 3
#define NC 3
#define BATCH 16384

// Layout: 32 lanes per element, each lane holds 8 complex amps; 2 elements
// per thread (ILP). Amplitude index a[7:0]: bits 0..2 = register index r
// (wires 0..2), bits 3..7 = lane sub-id q bits 0..4 (wires 3..7).
//
// Algebra:
//  - Layer 0 RY on |0..0> is a product state -> built directly (real).
//  - State stays real through layer-0 CNOT and enters RZ real.
//  - CNOT chain composed into one permutation pull:
//      src lane qs = ((q^(q<<1))&31) ^ (destRegBit2 ? 1 : 0)
//      src reg  rc = rc_base(r) ^ (laneBit4 ? 3 : 0),
//      rc_base bits = { r0, r0^r1, r1^r2 }
//  - RZ layer fused to one phase/amp; R[8]+sincos shared by both elements.
//  - Final CNOT+RZ dropped; CNOT folded into measurement signs:
//      z0: parity(r&6)^parity(q), z1: parity(r&3), z2: parity(r&7)

__global__ __launch_bounds__(256, 4) void vqc_kernel(
    const float* __restrict__ x, const float* __restrict__ qw,
    const float* __restrict__ W, const float* __restrict__ b,
    float* __restrict__ out)
{
  const int tid = threadIdx.x;
  const int q   = tid & 31;                      // lane within 32-group
  const int g   = blockIdx.x * 8 + (tid >> 5);   // group id; elems 2g, 2g+1

  // lanes q<8 hold x[e0*8+q]; lanes 8..15 hold x[e1*8+(q-8)] (contiguous)
  float xv = 0.f;
  if (q < 16) xv = x[g * 16 + q];

  const float PI = 3.14159265358979323846f;

  float sr[2][8], si[2][8];

  // composed-CNOT per-lane source indices
  const int  qs0    = (q ^ (q << 1)) & 31;
  const int  qs1    = qs0 ^ 1;
  const bool laneB7 = (q & 16) != 0;

  // ================= layer 0 =================
  {
    float cv, sv;
    __sincosf(0.5f * (PI * xv + qw[q & 7]), &sv, &cv);

    // ---- direct product-state build (real) ----
    #pragma unroll
    for (int e = 0; e < 2; ++e) {
      float cw[8], sw[8];
      #pragma unroll
      for (int w = 0; w < 8; ++w) {
        cw[w] = __shfl(cv, 8 * e + w, 32);
        sw[w] = __shfl(sv, 8 * e + w, 32);
      }
      float P = ((q & 1)  ? sw[3] : cw[3]);
      P      *= ((q & 2)  ? sw[4] : cw[4]);
      P      *= ((q & 4)  ? sw[5] : cw[5]);
      P      *= ((q & 8)  ? sw[6] : cw[6]);
      P      *= ((q & 16) ? sw[7] : cw[7]);
      sr[e][0] = P * cw[0];
      sr[e][1] = P * sw[0];
      #pragma unroll
      for (int r = 0; r < 2; ++r) { sr[e][r+2] = sr[e][r] * sw[1]; sr[e][r] *= cw[1]; }
      #pragma unroll
      for (int r = 0; r < 4; ++r) { sr[e][r+4] = sr[e][r] * sw[2]; sr[e][r] *= cw[2]; }
    }

    // ---- composed CNOT (real state) ----
    #pragma unroll
    for (int e = 0; e < 2; ++e) {
      float nr[8];
      #pragma unroll
      for (int r = 0; r < 8; ++r) {
        const int rc0  = (r & 1) | (((r ^ (r >> 1)) & 1) << 1)
                       | ((((r >> 1) ^ (r >> 2)) & 1) << 2);
        const int rc1  = rc0 ^ 3;
        const int qsel = (r & 4) ? qs1 : qs0;
        const float u0 = __shfl(sr[e][rc0], qsel, 32);
        const float u1 = __shfl(sr[e][rc1], qsel, 32);
        nr[r] = laneB7 ? u1 : u0;
      }
      #pragma unroll
      for (int r = 0; r < 8; ++r) sr[e][r] = nr[r];
    }

    // ---- fused RZ (shared angles), real -> complex ----
    float R[8];
    {
      const float h0 = 0.5f * qw[NQ + 0], h1 = 0.5f * qw[NQ + 1];
      const float h2 = 0.5f * qw[NQ + 2], h3 = 0.5f * qw[NQ + 3];
      const float h4 = 0.5f * qw[NQ + 4], h5 = 0.5f * qw[NQ + 5];
      const float h6 = 0.5f * qw[NQ + 6], h7 = 0.5f * qw[NQ + 7];
      const float Lq = ((q & 1)  ? h3 : -h3) + ((q & 2)  ? h4 : -h4)
                     + ((q & 4)  ? h5 : -h5) + ((q & 8)  ? h6 : -h6)
                     + ((q & 16) ? h7 : -h7);
      R[0] = Lq - h0; R[1] = Lq + h0;
      #pragma unroll
      for (int r = 0; r < 2; ++r) { R[r + 2] = R[r] + h1; R[r] -= h1; }
      #pragma unroll
      for (int r = 0; r < 4; ++r) { R[r + 4] = R[r] + h2; R[r] -= h2; }
    }
    #pragma unroll
    for (int r = 0; r < 8; ++r) {
      float sp, cp;
      __sincosf(R[r], &sp, &cp);
      #pragma unroll
      for (int e = 0; e < 2; ++e) {
        si[e][r] = sp * sr[e][r];
        sr[e][r] = cp * sr[e][r];
      }
    }
  }

  // ================= layers 1, 2 =================
  #pragma unroll
  for (int layer = 1; layer < NL; ++layer) {
    const int base = layer * 2 * NQ;
    float cv, sv;
    __sincosf(0.5f * (PI * xv + qw[base + (q & 7)]), &sv, &cv);

    // ---- RY cascade ----
    #pragma unroll
    for (int e = 0; e < 2; ++e) {
      // reg wires 0..2
      #pragma unroll
      for (int w = 0; w < 3; ++w) {
        const float c = __shfl(cv, 8 * e + w, 32);
        const float s = __shfl(sv, 8 * e + w, 32);
        const int m = 1 << w;
        #pragma unroll
        for (int r = 0; r < 8; ++r) {
          if (!(r & m)) {
            const int r1 = r | m;
            const float a0r = sr[e][r],  a0i = si[e][r];
            const float a1r = sr[e][r1], a1i = si[e][r1];
            sr[e][r]  = c * a0r - s * a1r;
            si[e][r]  = c * a0i - s * a1i;
            sr[e][r1] = s * a0r + c * a1r;
            si[e][r1] = s * a0i + c * a1i;
          }
        }
      }
      // lane wires 3..7
      #pragma unroll
      for (int w = 3; w < 8; ++w) {
        const float c = __shfl(cv, 8 * e + w, 32);
        const float s = __shfl(sv, 8 * e + w, 32);
        const int lm = 1 << (w - 3);
        const float ss = (q & lm) ? s : -s;
        #pragma unroll
        for (int r = 0; r < 8; ++r) {
          const float otr = __shfl_xor(sr[e][r], lm);
          const float oti = __shfl_xor(si[e][r], lm);
          sr[e][r] = c * sr[e][r] + ss * otr;
          si[e][r] = c * si[e][r] + ss * oti;
        }
      }
    }

    if (layer < NL - 1) {
      // ---- composed CNOT (complex) ----
      #pragma unroll
      for (int e = 0; e < 2; ++e) {
        float nr[8], ni[8];
        #pragma unroll
        for (int r = 0; r < 8; ++r) {
          const int rc0  = (r & 1) | (((r ^ (r >> 1)) & 1) << 1)
                         | ((((r >> 1) ^ (r >> 2)) & 1) << 2);
          const int rc1  = rc0 ^ 3;
          const int qsel = (r & 4) ? qs1 : qs0;
          const float u0r = __shfl(sr[e][rc0], qsel, 32);
          const float u0i = __shfl(si[e][rc0], qsel, 32);
          const float u1r = __shfl(sr[e][rc1], qsel, 32);
          const float u1i = __shfl(si[e][rc1], qsel, 32);
          nr[r] = laneB7 ? u1r : u0r;
          ni[r] = laneB7 ? u1i : u0i;
        }
        #pragma unroll
        for (int r = 0; r < 8; ++r) { sr[e][r] = nr[r]; si[e][r] = ni[r]; }
      }

      // ---- fused RZ (shared angles), complex ----
      float R[8];
      {
        const float h0 = 0.5f * qw[base + NQ + 0], h1 = 0.5f * qw[base + NQ + 1];
        const float h2 = 0.5f * qw[base + NQ + 2], h3 = 0.5f * qw[base + NQ + 3];
        const float h4 = 0.5f * qw[base + NQ + 4], h5 = 0.5f * qw[base + NQ + 5];
        const float h6 = 0.5f * qw[base + NQ + 6], h7 = 0.5f * qw[base + NQ + 7];
        const float Lq = ((q & 1)  ? h3 : -h3) + ((q & 2)  ? h4 : -h4)
                       + ((q & 4)  ? h5 : -h5) + ((q & 8)  ? h6 : -h6)
                       + ((q & 16) ? h7 : -h7);
        R[0] = Lq - h0; R[1] = Lq + h0;
        #pragma unroll
        for (int r = 0; r < 2; ++r) { R[r + 2] = R[r] + h1; R[r] -= h1; }
        #pragma unroll
        for (int r = 0; r < 4; ++r) { R[r + 4] = R[r] + h2; R[r] -= h2; }
      }
      #pragma unroll
      for (int r = 0; r < 8; ++r) {
        float sp, cp;
        __sincosf(R[r], &sp, &cp);
        #pragma unroll
        for (int e = 0; e < 2; ++e) {
          const float re = sr[e][r], im = si[e][r];
          sr[e][r] = cp * re - sp * im;
          si[e][r] = cp * im + sp * re;
        }
      }
    }
  }

  // ================= measurement =================
  float za0 = 0.f, za1 = 0.f, za2 = 0.f;   // element 0
  float zb0 = 0.f, zb1 = 0.f, zb2 = 0.f;   // element 1
  #pragma unroll
  for (int r = 0; r < 8; ++r) {
    const float pa = sr[0][r] * sr[0][r] + si[0][r] * si[0][r];
    const float pb = sr[1][r] * sr[1][r] + si[1][r] * si[1][r];
    const float g0 = (__popc(r & 6) & 1) ? -1.f : 1.f;
    const float g1 = (__popc(r & 3) & 1) ? -1.f : 1.f;
    const float g2 = (__popc(r & 7) & 1) ? -1.f : 1.f;
    za0 += g0 * pa; za1 += g1 * pa; za2 += g2 * pa;
    zb0 += g0 * pb; zb1 += g1 * pb; zb2 += g2 * pb;
  }
  if (__popc(q) & 1) { za0 = -za0; zb0 = -zb0; }

  #pragma unroll
  for (int m = 1; m <= 16; m <<= 1) {
    za0 += __shfl_xor(za0, m); za1 += __shfl_xor(za1, m); za2 += __shfl_xor(za2, m);
    zb0 += __shfl_xor(zb0, m); zb1 += __shfl_xor(zb1, m); zb2 += __shfl_xor(zb2, m);
  }

  // lanes 0..2 write element 2g classes; lanes 8..10 write element 2g+1
  const int c = q & 7;
  if (c < NC && q < 16) {
    const float zz0 = (q & 8) ? zb0 : za0;
    const float zz1 = (q & 8) ? zb1 : za1;
    const float zz2 = (q & 8) ? zb2 : za2;
    const int e = g * 2 + ((q >> 3) & 1);
    out[e * NC + c] = b[c] + W[c * 3 + 0] * zz0 + W[c * 3 + 1] * zz1
                           + W[c * 3 + 2] * zz2;
  }
}

extern "C" void kernel_launch(void* const* d_in, const int* in_sizes, int n_in,
                              void* d_out, int out_size, void* d_ws, size_t ws_size,
                              hipStream_t stream) {
  const float* x  = (const float*)d_in[0];
  const float* qw = (const float*)d_in[1];
  const float* W  = (const float*)d_in[2];
  const float* b  = (const float*)d_in[3];
  float* out = (float*)d_out;

  dim3 grid(BATCH / 16);   // 8 groups/block * 2 elements/group
  vqc_kernel<<<grid, 256, 0, stream>>>(x, qw, W, b, out);
}

// Round 4
// 21.300 us; speedup vs baseline: 2.0918x; 1.3403x over previous
//
#include <hip/hip_runtime.h>
#include <math.h>

#define NQ 8
#define NL 3
#define NC 3
#define BATCH 16384

// Layout (l=4): 16 lanes per element, each lane holds 16 complex amps.
// Amplitude index a[7:0]: bits 0..3 = register index r (wires 0..3),
//                         bits 4..7 = lane sub-id q (wires 4..7).
//
// vs round 3:
//  - All RY angle broadcasts eliminated: each thread loads its element's x
//    (2x float4) and computes all 8 sincos per layer itself (trans pipe).
//  - xor-shuffles for masks 1,2,8 use DPP (VALU pipe): quad_perm 0xB1 /
//    0x4E, row_ror:8 (0x128). Only mask 4 uses ds_swizzle (DS pipe).
//  - Round-2-verified algebra kept: product-state layer 0 (real through
//    first CNOT+RZ), composed CNOT pull, fused RZ butterfly, final
//    CNOT+RZ folded into measurement signs.

__device__ __forceinline__ float dpp_f(float v, const int ctrl) {
  // compile-time ctrl required; callers pass literals via template below
  return v;
}

template<int CTRL>
__device__ __forceinline__ float dpp_mov(float v) {
  int r = __builtin_amdgcn_update_dpp(0, __builtin_bit_cast(int, v),
                                      CTRL, 0xF, 0xF, true);
  return __builtin_bit_cast(float, r);
}

__device__ __forceinline__ float swz_xor4(float v) {
  int r = __builtin_amdgcn_ds_swizzle(__builtin_bit_cast(int, v), 0x101F);
  return __builtin_bit_cast(float, r);
}

template<int M>
__device__ __forceinline__ float shx(float v) {
  if constexpr (M == 1)      return dpp_mov<0xB1>(v);   // quad_perm [1,0,3,2]
  else if constexpr (M == 2) return dpp_mov<0x4E>(v);   // quad_perm [2,3,0,1]
  else if constexpr (M == 8) return dpp_mov<0x128>(v);  // row_ror:8
  else                       return swz_xor4(v);        // M == 4: ds_swizzle
}

template<int W>
__device__ __forceinline__ void reg_ry(float (&sr)[16], float (&si)[16],
                                       float c, float s) {
  constexpr int m = 1 << W;
  #pragma unroll
  for (int r = 0; r < 16; ++r) {
    if (!(r & m)) {
      const int r1 = r | m;
      const float a0r = sr[r],  a0i = si[r];
      const float a1r = sr[r1], a1i = si[r1];
      sr[r]  = c * a0r - s * a1r;
      si[r]  = c * a0i - s * a1i;
      sr[r1] = s * a0r + c * a1r;
      si[r1] = s * a0i + c * a1i;
    }
  }
}

template<int M>
__device__ __forceinline__ void lane_ry(float (&sr)[16], float (&si)[16],
                                        float c, float s, int q) {
  const float ss = (q & M) ? s : -s;
  #pragma unroll
  for (int r = 0; r < 16; ++r) {
    const float otr = shx<M>(sr[r]);
    const float oti = shx<M>(si[r]);
    sr[r] = c * sr[r] + ss * otr;
    si[r] = c * si[r] + ss * oti;
  }
}

__global__ __launch_bounds__(256, 4) void vqc_kernel(
    const float* __restrict__ x, const float* __restrict__ qw,
    const float* __restrict__ W, const float* __restrict__ b,
    float* __restrict__ out)
{
  const int tid  = threadIdx.x;
  const int q    = tid & 15;
  const int elem = blockIdx.x * 16 + (tid >> 4);

  const float PI = 3.14159265358979323846f;

  // per-thread copy of this element's features (L1-broadcast across lanes)
  float xs[8];
  {
    const float4 x0 = *(const float4*)(x + elem * 8);
    const float4 x1 = *(const float4*)(x + elem * 8 + 4);
    xs[0] = x0.x; xs[1] = x0.y; xs[2] = x0.z; xs[3] = x0.w;
    xs[4] = x1.x; xs[5] = x1.y; xs[6] = x1.z; xs[7] = x1.w;
  }

  float sr[16], si[16];

  // composed-CNOT per-lane source indices (round-2 verified)
  const int  qs0    = (q ^ (q << 1)) & 15;
  const int  qs1    = qs0 ^ 1;
  const bool laneB7 = (q & 8) != 0;

  // ===================== layer 0 =====================
  {
    float cw[8], sw[8];
    #pragma unroll
    for (int w = 0; w < 8; ++w)
      __sincosf(0.5f * (PI * xs[w] + qw[w]), &sw[w], &cw[w]);

    // product-state build (real)
    float P = ((q & 1) ? sw[4] : cw[4]);
    P      *= ((q & 2) ? sw[5] : cw[5]);
    P      *= ((q & 4) ? sw[6] : cw[6]);
    P      *= ((q & 8) ? sw[7] : cw[7]);
    sr[0] = P * cw[0];
    sr[1] = P * sw[0];
    #pragma unroll
    for (int r = 0; r < 2; ++r) { sr[r + 2] = sr[r] * sw[1]; sr[r] *= cw[1]; }
    #pragma unroll
    for (int r = 0; r < 4; ++r) { sr[r + 4] = sr[r] * sw[2]; sr[r] *= cw[2]; }
    #pragma unroll
    for (int r = 0; r < 8; ++r) { sr[r + 8] = sr[r] * sw[3]; sr[r] *= cw[3]; }

    // composed CNOT (real state)
    {
      float nr[16];
      #pragma unroll
      for (int r = 0; r < 16; ++r) {
        const int rc0  = (r ^ (r << 1)) & 15;
        const int rc1  = rc0 ^ 3;
        const int qsel = (r & 8) ? qs1 : qs0;
        const float u0 = __shfl(sr[rc0], qsel, 16);
        const float u1 = __shfl(sr[rc1], qsel, 16);
        nr[r] = laneB7 ? u1 : u0;
      }
      #pragma unroll
      for (int r = 0; r < 16; ++r) sr[r] = nr[r];
    }

    // fused RZ (real -> complex)
    {
      const float h0 = 0.5f * qw[NQ + 0], h1 = 0.5f * qw[NQ + 1];
      const float h2 = 0.5f * qw[NQ + 2], h3 = 0.5f * qw[NQ + 3];
      const float h4 = 0.5f * qw[NQ + 4], h5 = 0.5f * qw[NQ + 5];
      const float h6 = 0.5f * qw[NQ + 6], h7 = 0.5f * qw[NQ + 7];
      const float Lq = ((q & 1) ? h4 : -h4) + ((q & 2) ? h5 : -h5)
                     + ((q & 4) ? h6 : -h6) + ((q & 8) ? h7 : -h7);
      float R[16];
      R[0] = Lq - h0; R[1] = Lq + h0;
      #pragma unroll
      for (int r = 0; r < 2; ++r) { R[r + 2] = R[r] + h1; R[r] -= h1; }
      #pragma unroll
      for (int r = 0; r < 4; ++r) { R[r + 4] = R[r] + h2; R[r] -= h2; }
      #pragma unroll
      for (int r = 0; r < 8; ++r) { R[r + 8] = R[r] + h3; R[r] -= h3; }
      #pragma unroll
      for (int r = 0; r < 16; ++r) {
        float sp, cp;
        __sincosf(R[r], &sp, &cp);
        si[r] = sp * sr[r];
        sr[r] = cp * sr[r];
      }
    }
  }

  // ===================== layers 1, 2 =====================
  #pragma unroll
  for (int layer = 1; layer < NL; ++layer) {
    const int base = layer * 2 * NQ;

    float cw[8], sw[8];
    #pragma unroll
    for (int w = 0; w < 8; ++w)
      __sincosf(0.5f * (PI * xs[w] + qw[base + w]), &sw[w], &cw[w]);

    // RY: reg wires 0..3 (pure VALU)
    reg_ry<0>(sr, si, cw[0], sw[0]);
    reg_ry<1>(sr, si, cw[1], sw[1]);
    reg_ry<2>(sr, si, cw[2], sw[2]);
    reg_ry<3>(sr, si, cw[3], sw[3]);
    // RY: lane wires 4..7 (DPP for masks 1,2,8; ds_swizzle for 4)
    lane_ry<1>(sr, si, cw[4], sw[4], q);
    lane_ry<2>(sr, si, cw[5], sw[5], q);
    lane_ry<4>(sr, si, cw[6], sw[6], q);
    lane_ry<8>(sr, si, cw[7], sw[7], q);

    if (layer < NL - 1) {
      // composed CNOT (complex)
      {
        float nr[16], ni[16];
        #pragma unroll
        for (int r = 0; r < 16; ++r) {
          const int rc0  = (r ^ (r << 1)) & 15;
          const int rc1  = rc0 ^ 3;
          const int qsel = (r & 8) ? qs1 : qs0;
          const float u0r = __shfl(sr[rc0], qsel, 16);
          const float u0i = __shfl(si[rc0], qsel, 16);
          const float u1r = __shfl(sr[rc1], qsel, 16);
          const float u1i = __shfl(si[rc1], qsel, 16);
          nr[r] = laneB7 ? u1r : u0r;
          ni[r] = laneB7 ? u1i : u0i;
        }
        #pragma unroll
        for (int r = 0; r < 16; ++r) { sr[r] = nr[r]; si[r] = ni[r]; }
      }

      // fused RZ (complex)
      {
        const float h0 = 0.5f * qw[base + NQ + 0], h1 = 0.5f * qw[base + NQ + 1];
        const float h2 = 0.5f * qw[base + NQ + 2], h3 = 0.5f * qw[base + NQ + 3];
        const float h4 = 0.5f * qw[base + NQ + 4], h5 = 0.5f * qw[base + NQ + 5];
        const float h6 = 0.5f * qw[base + NQ + 6], h7 = 0.5f * qw[base + NQ + 7];
        const float Lq = ((q & 1) ? h4 : -h4) + ((q & 2) ? h5 : -h5)
                       + ((q & 4) ? h6 : -h6) + ((q & 8) ? h7 : -h7);
        float R[16];
        R[0] = Lq - h0; R[1] = Lq + h0;
        #pragma unroll
        for (int r = 0; r < 2; ++r) { R[r + 2] = R[r] + h1; R[r] -= h1; }
        #pragma unroll
        for (int r = 0; r < 4; ++r) { R[r + 4] = R[r] + h2; R[r] -= h2; }
        #pragma unroll
        for (int r = 0; r < 8; ++r) { R[r + 8] = R[r] + h3; R[r] -= h3; }
        #pragma unroll
        for (int r = 0; r < 16; ++r) {
          float sp, cp;
          __sincosf(R[r], &sp, &cp);
          const float re = sr[r], im = si[r];
          sr[r] = cp * re - sp * im;
          si[r] = cp * im + sp * re;
        }
      }
    }
  }

  // ============ measurement (final CNOT folded into signs) ============
  float z0 = 0.f, z1 = 0.f, z2 = 0.f;
  #pragma unroll
  for (int r = 0; r < 16; ++r) {
    const float p = sr[r] * sr[r] + si[r] * si[r];
    z0 += (__popc(r & 14) & 1) ? -p : p;
    z1 += (__popc(r & 3)  & 1) ? -p : p;
    z2 += (__popc(r & 7)  & 1) ? -p : p;
  }
  if (__popc(q) & 1) z0 = -z0;

  // 16-lane butterfly reduce: DPP for 1,2,8; swizzle for 4
  z0 += shx<1>(z0); z1 += shx<1>(z1); z2 += shx<1>(z2);
  z0 += shx<2>(z0); z1 += shx<2>(z1); z2 += shx<2>(z2);
  z0 += shx<4>(z0); z1 += shx<4>(z1); z2 += shx<4>(z2);
  z0 += shx<8>(z0); z1 += shx<8>(z1); z2 += shx<8>(z2);

  if (q < NC) {
    out[elem * NC + q] = b[q] + W[q * 3 + 0] * z0 + W[q * 3 + 1] * z1
                              + W[q * 3 + 2] * z2;
  }
}

extern "C" void kernel_launch(void* const* d_in, const int* in_sizes, int n_in,
                              void* d_out, int out_size, void* d_ws, size_t ws_size,
                              hipStream_t stream) {
  const float* x  = (const float*)d_in[0];
  const float* qw = (const float*)d_in[1];
  const float* W  = (const float*)d_in[2];
  const float* b  = (const float*)d_in[3];
  float* out = (float*)d_out;

  dim3 grid(BATCH / 16);   // 16 elements per 256-thread block
  vqc_kernel<<<grid, 256, 0, stream>>>(x, qw, W, b, out);
}